// Round 4
// baseline (623.651 us; speedup 1.0000x reference)
//
#include <hip/hip_runtime.h>

// Project2Dto3D: out[b,c,v] = sum over pixels hw with proj[hw]==v of feat[b,c,hw]
// B=4, C=128, H=240, W=320, V=60*36*60=129600
//
// CSR build -> fused transpose+permute to channel-last featP[j][bc] ->
// fully-coalesced streaming gather. Random access never touches <64B units.

static constexpr int HW = 240 * 320;      // 76800
static constexpr int V  = 60 * 36 * 60;   // 129600
static constexpr int B  = 4;
static constexpr int C  = 128;
static constexpr int BC = B * C;          // 512
static constexpr int NBV = (V + 255) / 256;    // 507
static constexpr int NHWT = HW / 64;      // 1200 hw-tiles
static constexpr int NBCT = BC / 64;      // 8 bc-tiles
static constexpr int VT = 16;             // voxels per gather tile
static constexpr int NVT = V / VT;        // 8100

typedef float f4 __attribute__((ext_vector_type(4)));

// ---------------------------------------------------------------------------
__global__ void __launch_bounds__(256) zero_kernel(int* __restrict__ cnt) {
    int i = blockIdx.x * 256 + threadIdx.x;
    if (i < V) cnt[i] = 0;
}

__global__ void __launch_bounds__(256) count_kernel(const int* __restrict__ idx,
                                                    int* __restrict__ cnt) {
    int hw = blockIdx.x * 256 + threadIdx.x;
    if (hw < HW) atomicAdd(&cnt[idx[hw]], 1);
}

__global__ void __launch_bounds__(256) blocksum_kernel(const int* __restrict__ cnt,
                                                       int* __restrict__ bsum) {
    int i = blockIdx.x * 256 + threadIdx.x;
    int v = (i < V) ? cnt[i] : 0;
#pragma unroll
    for (int d = 32; d > 0; d >>= 1) v += __shfl_down(v, d, 64);
    __shared__ int ws[4];
    if ((threadIdx.x & 63) == 0) ws[threadIdx.x >> 6] = v;
    __syncthreads();
    if (threadIdx.x == 0) bsum[blockIdx.x] = ws[0] + ws[1] + ws[2] + ws[3];
}

__global__ void __launch_bounds__(512) scan_bsum_kernel(int* __restrict__ bsum) {
    __shared__ int sm[512];
    int t = threadIdx.x;
    int v = (t < NBV) ? bsum[t] : 0;
    sm[t] = v;
    __syncthreads();
    for (int d = 1; d < 512; d <<= 1) {
        int x = (t >= d) ? sm[t - d] : 0;
        __syncthreads();
        sm[t] += x;
        __syncthreads();
    }
    if (t < NBV) bsum[t] = sm[t] - v;   // exclusive
}

// off (= cnt, in place) becomes exclusive offsets; cursor copies; off[V]=HW sentinel
__global__ void __launch_bounds__(256) scatter_off_kernel(int* __restrict__ cnt,
                                                          const int* __restrict__ bsum,
                                                          int* __restrict__ cursor) {
    int i = blockIdx.x * 256 + threadIdx.x;
    int c = (i < V) ? cnt[i] : 0;
    int lane = threadIdx.x & 63, w = threadIdx.x >> 6;
    int inc = c;
#pragma unroll
    for (int d = 1; d < 64; d <<= 1) {
        int x = __shfl_up(inc, d, 64);
        if (lane >= d) inc += x;
    }
    __shared__ int wsum[4];
    if (lane == 63) wsum[w] = inc;
    __syncthreads();
    int woff = 0;
    for (int k = 0; k < w; ++k) woff += wsum[k];
    int excl = inc - c + woff + bsum[blockIdx.x];
    if (i < V) { cnt[i] = excl; cursor[i] = excl; }
    if (i == 0) cnt[V] = HW;
}

// rank[hw] = CSR position of pixel hw (inverse permutation, coalesced write)
__global__ void __launch_bounds__(256) rank_kernel(const int* __restrict__ idx,
                                                   int* __restrict__ cursor,
                                                   int* __restrict__ rank) {
    int hw = blockIdx.x * 256 + threadIdx.x;
    if (hw < HW) {
        int v = idx[hw];
        rank[hw] = atomicAdd(&cursor[v], 1);
    }
}

// Fused transpose + permute: featP[rank[hw]][bc] = feat[bc][hw].
// 64x64 tile; reads coalesced 256B, writes 256B contiguous at random rows.
__global__ void __launch_bounds__(256) transpose_perm_kernel(
        const float* __restrict__ feat, const int* __restrict__ rank,
        float* __restrict__ featP) {
    __shared__ float tile[64][65];
    int hw0 = blockIdx.x * 64;
    int bc0 = blockIdx.y * 64;
    int c  = threadIdx.x & 63;
    int r0 = threadIdx.x >> 6;
#pragma unroll
    for (int k = 0; k < 16; ++k) {
        int r = r0 + (k << 2);
        tile[r][c] = feat[(long long)(bc0 + r) * HW + hw0 + c];
    }
    __syncthreads();
#pragma unroll
    for (int k = 0; k < 16; ++k) {
        int h = r0 + (k << 2);
        int dst = rank[hw0 + h];
        featP[(long long)dst * BC + bc0 + c] = tile[c][h];
    }
}

// Gather: block = 16-voxel tile, thread t = channel bc=t. Rows of featP for
// this tile are CONTIGUOUS [off[v0], off[v0+16]) and read fully coalesced.
__global__ void __launch_bounds__(512) gatherT_kernel(
        const float* __restrict__ featP, const int* __restrict__ off,
        float* __restrict__ out) {
    int v0 = blockIdx.x * VT;
    int t = threadIdx.x;
    float acc[VT];
    int jprev = off[v0];
#pragma unroll
    for (int i = 0; i < VT; ++i) {
        int j1 = off[v0 + i + 1];
        float a = 0.f;
        for (int j = jprev; j < j1; ++j)
            a += featP[(long long)j * BC + t];
        acc[i] = a;
        jprev = j1;
    }
    long long base = (long long)t * V + v0;
#pragma unroll
    for (int q = 0; q < 4; ++q) {
        f4 val = { acc[4*q], acc[4*q+1], acc[4*q+2], acc[4*q+3] };
        __builtin_nontemporal_store(val, (f4*)(out + base + 4*q));
    }
}

// ---------------------------------------------------------------------------
// Fallback gather (round-3 path) if workspace can't hold featP.
static constexpr int BCPT = 8;
static constexpr int NG = BC / BCPT;
static constexpr int NXCD = 8;
static constexpr int GPX = NG / NXCD;

__global__ void __launch_bounds__(256) perm_kernel(const int* __restrict__ idx,
                                                   int* __restrict__ cursor,
                                                   int* __restrict__ perm) {
    int hw = blockIdx.x * 256 + threadIdx.x;
    if (hw < HW) {
        int v = idx[hw];
        int pos = atomicAdd(&cursor[v], 1);
        perm[pos] = hw;
    }
}

__global__ void __launch_bounds__(256) gather_kernel(const float* __restrict__ feat,
                                                     const int* __restrict__ off,
                                                     const int* __restrict__ perm,
                                                     float* __restrict__ out) {
    int bid  = blockIdx.x;
    int xcd  = bid & (NXCD - 1);
    int lid  = bid >> 3;
    int gloc = lid / NBV;
    int vblk = lid - gloc * NBV;
    int g    = xcd * GPX + gloc;
    int v    = vblk * 256 + threadIdx.x;
    if (v >= V) return;
    int bc0 = g * BCPT;
    int j0 = off[v];
    int j1 = off[v + 1];
    const float* f = feat + (long long)bc0 * HW;
    float s[BCPT];
#pragma unroll
    for (int k = 0; k < BCPT; ++k) s[k] = 0.f;
    for (int j = j0; j < j1; ++j) {
        int p = perm[j];
#pragma unroll
        for (int k = 0; k < BCPT; ++k) s[k] += f[p + k * HW];
    }
    long long o = (long long)bc0 * V + v;
#pragma unroll
    for (int k = 0; k < BCPT; ++k)
        __builtin_nontemporal_store(s[k], &out[o + (long long)k * V]);
}

extern "C" void kernel_launch(void* const* d_in, const int* in_sizes, int n_in,
                              void* d_out, int out_size, void* d_ws, size_t ws_size,
                              hipStream_t stream) {
    const float* feat = (const float*)d_in[0];   // [4,128,240,320] f32
    const int*   idx  = (const int*)d_in[1];     // [240,320] int
    float*       out  = (float*)d_out;           // [4,128,129600] f32

    // workspace (ints): off[V+1] | cursor[V] | rank[HW] | bsum[512] | featP
    int* off    = (int*)d_ws;
    int* cursor = off + (V + 1);
    int* rank   = cursor + V;               // also 'perm' in fallback
    int* bsum   = rank + HW;
    size_t hdr_bytes = ((size_t)(V + 1 + V + HW + 512) * 4 + 255) & ~(size_t)255;
    float* featP = (float*)((char*)d_ws + hdr_bytes);
    size_t need = hdr_bytes + (size_t)HW * BC * sizeof(float);

    zero_kernel       <<<NBV, 256, 0, stream>>>(off);
    count_kernel      <<<(HW + 255) / 256, 256, 0, stream>>>(idx, off);
    blocksum_kernel   <<<NBV, 256, 0, stream>>>(off, bsum);
    scan_bsum_kernel  <<<1, 512, 0, stream>>>(bsum);
    scatter_off_kernel<<<NBV, 256, 0, stream>>>(off, bsum, cursor);

    if (ws_size >= need) {
        rank_kernel<<<(HW + 255) / 256, 256, 0, stream>>>(idx, cursor, rank);
        dim3 tgrid(NHWT, NBCT);
        transpose_perm_kernel<<<tgrid, 256, 0, stream>>>(feat, rank, featP);
        gatherT_kernel<<<NVT, 512, 0, stream>>>(featP, off, out);
    } else {
        perm_kernel<<<(HW + 255) / 256, 256, 0, stream>>>(idx, cursor, rank);
        gather_kernel<<<NXCD * GPX * NBV, 256, 0, stream>>>(feat, off, rank, out);
    }
}

// Round 5
// 154.924 us; speedup vs baseline: 4.0255x; 4.0255x over previous
//
#include <hip/hip_runtime.h>

// Project2Dto3D: out[b,c,v] = sum over pixels hw with proj[hw]==v of feat[b,c,hw]
// B=4, C=128, H=240, W=320, V=60*36*60=129600
//
// CSR build -> fused transpose+permute to channel-last featP[j][bc] ->
// coalesced streaming gather with LDS-staged full-line output writes.

static constexpr int HW = 240 * 320;      // 76800
static constexpr int V  = 60 * 36 * 60;   // 129600
static constexpr int B  = 4;
static constexpr int C  = 128;
static constexpr int BC = B * C;          // 512
static constexpr int NBV = (V + 255) / 256;    // 507
static constexpr int NHWT = HW / 64;      // 1200 hw-tiles
static constexpr int NBCT = BC / 64;      // 8 bc-tiles
static constexpr int VT = 16;             // voxels per gather tile
static constexpr int NVT = V / VT;        // 8100
static constexpr int SMP = BC + 1;        // padded LDS row stride (513)

typedef float f4 __attribute__((ext_vector_type(4)));

// ---------------------------------------------------------------------------
__global__ void __launch_bounds__(256) zero_kernel(int* __restrict__ cnt) {
    int i = blockIdx.x * 256 + threadIdx.x;
    if (i < V) cnt[i] = 0;
}

__global__ void __launch_bounds__(256) count_kernel(const int* __restrict__ idx,
                                                    int* __restrict__ cnt) {
    int hw = blockIdx.x * 256 + threadIdx.x;
    if (hw < HW) atomicAdd(&cnt[idx[hw]], 1);
}

__global__ void __launch_bounds__(256) blocksum_kernel(const int* __restrict__ cnt,
                                                       int* __restrict__ bsum) {
    int i = blockIdx.x * 256 + threadIdx.x;
    int v = (i < V) ? cnt[i] : 0;
#pragma unroll
    for (int d = 32; d > 0; d >>= 1) v += __shfl_down(v, d, 64);
    __shared__ int ws[4];
    if ((threadIdx.x & 63) == 0) ws[threadIdx.x >> 6] = v;
    __syncthreads();
    if (threadIdx.x == 0) bsum[blockIdx.x] = ws[0] + ws[1] + ws[2] + ws[3];
}

__global__ void __launch_bounds__(512) scan_bsum_kernel(int* __restrict__ bsum) {
    __shared__ int sm[512];
    int t = threadIdx.x;
    int v = (t < NBV) ? bsum[t] : 0;
    sm[t] = v;
    __syncthreads();
    for (int d = 1; d < 512; d <<= 1) {
        int x = (t >= d) ? sm[t - d] : 0;
        __syncthreads();
        sm[t] += x;
        __syncthreads();
    }
    if (t < NBV) bsum[t] = sm[t] - v;   // exclusive
}

// off (= cnt, in place) becomes exclusive offsets; cursor copies; off[V]=HW sentinel
__global__ void __launch_bounds__(256) scatter_off_kernel(int* __restrict__ cnt,
                                                          const int* __restrict__ bsum,
                                                          int* __restrict__ cursor) {
    int i = blockIdx.x * 256 + threadIdx.x;
    int c = (i < V) ? cnt[i] : 0;
    int lane = threadIdx.x & 63, w = threadIdx.x >> 6;
    int inc = c;
#pragma unroll
    for (int d = 1; d < 64; d <<= 1) {
        int x = __shfl_up(inc, d, 64);
        if (lane >= d) inc += x;
    }
    __shared__ int wsum[4];
    if (lane == 63) wsum[w] = inc;
    __syncthreads();
    int woff = 0;
    for (int k = 0; k < w; ++k) woff += wsum[k];
    int excl = inc - c + woff + bsum[blockIdx.x];
    if (i < V) { cnt[i] = excl; cursor[i] = excl; }
    if (i == 0) cnt[V] = HW;
}

// rank[hw] = CSR position of pixel hw (inverse permutation, coalesced write)
__global__ void __launch_bounds__(256) rank_kernel(const int* __restrict__ idx,
                                                   int* __restrict__ cursor,
                                                   int* __restrict__ rank) {
    int hw = blockIdx.x * 256 + threadIdx.x;
    if (hw < HW) {
        int v = idx[hw];
        rank[hw] = atomicAdd(&cursor[v], 1);
    }
}

// Fused transpose + permute: featP[rank[hw]][bc] = feat[bc][hw].
// 64x64 tile; reads coalesced 256B/instr, writes 256B contiguous (4 full lines).
__global__ void __launch_bounds__(256) transpose_perm_kernel(
        const float* __restrict__ feat, const int* __restrict__ rank,
        float* __restrict__ featP) {
    __shared__ float tile[64][65];
    int hw0 = blockIdx.x * 64;
    int bc0 = blockIdx.y * 64;
    int c  = threadIdx.x & 63;
    int r0 = threadIdx.x >> 6;
#pragma unroll
    for (int k = 0; k < 16; ++k) {
        int r = r0 + (k << 2);
        tile[r][c] = feat[(long long)(bc0 + r) * HW + hw0 + c];
    }
    __syncthreads();
#pragma unroll
    for (int k = 0; k < 16; ++k) {
        int h = r0 + (k << 2);
        int dst = rank[hw0 + h];
        featP[(long long)dst * BC + bc0 + c] = tile[c][h];
    }
}

// Gather: block = 16-voxel tile, thread t = channel bc=t during accumulation.
// featP rows for the tile are contiguous [off[v0], off[v0+16]) -> coalesced.
// Output staged through LDS so every store instruction covers whole 64B lines.
__global__ void __launch_bounds__(512) gatherT_kernel(
        const float* __restrict__ featP, const int* __restrict__ off,
        float* __restrict__ out) {
    __shared__ float sm[VT][SMP];
    int v0 = blockIdx.x * VT;
    int t = threadIdx.x;
    float acc[VT];
    int jprev = off[v0];
#pragma unroll
    for (int i = 0; i < VT; ++i) {
        int j1 = off[v0 + i + 1];
        float a = 0.f;
        for (int j = jprev; j < j1; ++j)
            a += featP[(long long)j * BC + t];
        acc[i] = a;
        jprev = j1;
    }
#pragma unroll
    for (int i = 0; i < VT; ++i) sm[i][t] = acc[i];   // bank (i+t)%32: conflict-free
    __syncthreads();

    // Write phase: element e in [0, 512*4): bc = e>>2, vq = e&3.
    // Lanes 4k..4k+3 cover out[bc][v0..v0+15] = one full 64B line each group.
#pragma unroll
    for (int r = 0; r < 4; ++r) {
        int e  = r * 512 + t;
        int bc = e >> 2;
        int vq = e & 3;
        f4 val = { sm[vq * 4 + 0][bc], sm[vq * 4 + 1][bc],
                   sm[vq * 4 + 2][bc], sm[vq * 4 + 3][bc] };
        __builtin_nontemporal_store(val, (f4*)(out + (long long)bc * V + v0 + vq * 4));
    }
}

// ---------------------------------------------------------------------------
// Fallback gather (round-3 path) if workspace can't hold featP.
static constexpr int BCPT = 8;
static constexpr int NG = BC / BCPT;
static constexpr int NXCD = 8;
static constexpr int GPX = NG / NXCD;

__global__ void __launch_bounds__(256) perm_kernel(const int* __restrict__ idx,
                                                   int* __restrict__ cursor,
                                                   int* __restrict__ perm) {
    int hw = blockIdx.x * 256 + threadIdx.x;
    if (hw < HW) {
        int v = idx[hw];
        int pos = atomicAdd(&cursor[v], 1);
        perm[pos] = hw;
    }
}

__global__ void __launch_bounds__(256) gather_kernel(const float* __restrict__ feat,
                                                     const int* __restrict__ off,
                                                     const int* __restrict__ perm,
                                                     float* __restrict__ out) {
    int bid  = blockIdx.x;
    int xcd  = bid & (NXCD - 1);
    int lid  = bid >> 3;
    int gloc = lid / NBV;
    int vblk = lid - gloc * NBV;
    int g    = xcd * GPX + gloc;
    int v    = vblk * 256 + threadIdx.x;
    if (v >= V) return;
    int bc0 = g * BCPT;
    int j0 = off[v];
    int j1 = off[v + 1];
    const float* f = feat + (long long)bc0 * HW;
    float s[BCPT];
#pragma unroll
    for (int k = 0; k < BCPT; ++k) s[k] = 0.f;
    for (int j = j0; j < j1; ++j) {
        int p = perm[j];
#pragma unroll
        for (int k = 0; k < BCPT; ++k) s[k] += f[p + k * HW];
    }
    long long o = (long long)bc0 * V + v;
#pragma unroll
    for (int k = 0; k < BCPT; ++k)
        __builtin_nontemporal_store(s[k], &out[o + (long long)k * V]);
}

extern "C" void kernel_launch(void* const* d_in, const int* in_sizes, int n_in,
                              void* d_out, int out_size, void* d_ws, size_t ws_size,
                              hipStream_t stream) {
    const float* feat = (const float*)d_in[0];   // [4,128,240,320] f32
    const int*   idx  = (const int*)d_in[1];     // [240,320] int
    float*       out  = (float*)d_out;           // [4,128,129600] f32

    // workspace (ints): off[V+1] | cursor[V] | rank[HW] | bsum[512] | featP
    int* off    = (int*)d_ws;
    int* cursor = off + (V + 1);
    int* rank   = cursor + V;               // also 'perm' in fallback
    int* bsum   = rank + HW;
    size_t hdr_bytes = ((size_t)(V + 1 + V + HW + 512) * 4 + 255) & ~(size_t)255;
    float* featP = (float*)((char*)d_ws + hdr_bytes);
    size_t need = hdr_bytes + (size_t)HW * BC * sizeof(float);

    zero_kernel       <<<NBV, 256, 0, stream>>>(off);
    count_kernel      <<<(HW + 255) / 256, 256, 0, stream>>>(idx, off);
    blocksum_kernel   <<<NBV, 256, 0, stream>>>(off, bsum);
    scan_bsum_kernel  <<<1, 512, 0, stream>>>(bsum);
    scatter_off_kernel<<<NBV, 256, 0, stream>>>(off, bsum, cursor);

    if (ws_size >= need) {
        rank_kernel<<<(HW + 255) / 256, 256, 0, stream>>>(idx, cursor, rank);
        dim3 tgrid(NHWT, NBCT);
        transpose_perm_kernel<<<tgrid, 256, 0, stream>>>(feat, rank, featP);
        gatherT_kernel<<<NVT, 512, 0, stream>>>(featP, off, out);
    } else {
        perm_kernel<<<(HW + 255) / 256, 256, 0, stream>>>(idx, cursor, rank);
        gather_kernel<<<NXCD * GPX * NBV, 256, 0, stream>>>(feat, off, rank, out);
    }
}